// Round 2
// baseline (9658.110 us; speedup 1.0000x reference)
//
#include <hip/hip_runtime.h>
#include <math.h>

#define NC 64
#define NH 256
#define NW 256
#define NM 32
#define NKY 64
#define HW 65536

static constexpr float PI_F = 3.14159265358979323846f;

__device__ __forceinline__ float gelu_f(float x) {
  return 0.5f * x * (1.0f + erff(x * 0.70710678118654752f));
}

// ---- init: cos/sin table for inverse-x DFT: tab[k][x] = (cos, sin)(2*pi*k*x/256)
__global__ void k_tab(float2* __restrict__ tab) {
  int i = blockIdx.x * 256 + threadIdx.x;   // 32*256
  int k = i >> 8, x = i & 255;
  int a = (k * x) & 255;
  float s, c;
  sincosf((float)a * (PI_F / 128.f), &s, &c);
  tab[i] = make_float2(c, s);
}

// ---- init: transpose [4][64][64] (o,c) -> (c,o)
__global__ void k_transpose(const float* __restrict__ w, float* __restrict__ wT) {
  int i = blockIdx.x * 256 + threadIdx.x;   // 4*64*64
  int l = i >> 12, r = (i >> 6) & 63, c = i & 63;
  wT[l * 4096 + c * 64 + r] = w[l * 4096 + r * 64 + c];
}

// ---- lift: h[b,c,y,x] = x[b,y,x]*pw[c] + pb[c]   (b = chunk-local batch)
__global__ __launch_bounds__(256) void k_lift(const float* __restrict__ x,
                                              const float* __restrict__ pw,
                                              const float* __restrict__ pb,
                                              float* __restrict__ h) {
  int b = blockIdx.y;
  int yx = blockIdx.x * 256 + threadIdx.x;
  float v = x[(size_t)b * HW + yx];
  float* hp = h + (size_t)b * NC * HW + yx;
  for (int c = 0; c < NC; ++c) hp[(size_t)c * HW] = v * pw[c] + pb[c];
}

// ---- forward x-DFT (real -> 32 complex modes), phase recurrence
__global__ __launch_bounds__(256) void k_fx(const float* __restrict__ h, float2* __restrict__ T1) {
  int ytile = blockIdx.x & 15;        // 16 row-tiles of 16
  int c = blockIdx.x >> 4;            // 0..63
  int bc = blockIdx.y * NC + c;
  const float* src = h + (size_t)bc * HW + ytile * (16 * NW);
  __shared__ float rows[16 * NW];
  for (int i = threadIdx.x; i < 16 * NW; i += 256) rows[i] = src[i];
  __syncthreads();
  int kx = threadIdx.x & 31;
  int y0 = threadIdx.x >> 5;  // 0..7
  float sd_, cd_;
  sincosf((float)kx * (PI_F / 128.f), &sd_, &cd_);
  float cd = cd_, sd = -sd_;           // rotation e^{-i*2pi*kx/256}
  const float* r0 = rows + y0 * NW;
  const float* r1 = rows + (y0 + 8) * NW;
  float cr = 1.f, ci = 0.f;
  float a0r = 0.f, a0i = 0.f, a1r = 0.f, a1i = 0.f;
#pragma unroll 4
  for (int xx = 0; xx < NW; ++xx) {
    float v0 = r0[xx], v1 = r1[xx];
    a0r += v0 * cr; a0i += v0 * ci;
    a1r += v1 * cr; a1i += v1 * ci;
    float nr = cr * cd - ci * sd; ci = ci * cd + cr * sd; cr = nr;
  }
  int ybase = ytile * 16;
  float2* dst = T1 + (size_t)bc * NH * NM;
  dst[(ybase + y0) * NM + kx]     = make_float2(a0r, a0i);
  dst[(ybase + y0 + 8) * NM + kx] = make_float2(a1r, a1i);
}

// ---- forward y-DFT (256 complex -> 64 kept modes) per (b,c)
__global__ __launch_bounds__(512) void k_fy(const float2* __restrict__ T1, float2* __restrict__ Xft) {
  int bc = blockIdx.y * NC + blockIdx.x;
  __shared__ float2 t[NH * NM];   // 64 KB
  const float2* src = T1 + (size_t)bc * (NH * NM);
  for (int i = threadIdx.x; i < NH * NM; i += 512) t[i] = src[i];
  __syncthreads();
  int kx = threadIdx.x & 31;
  int kyl = threadIdx.x >> 5;     // 0..15
  float2* dst = Xft + (size_t)bc * (NKY * NM);
  for (int p = 0; p < 4; ++p) {
    int kyi = p * 16 + kyl;
    int ky = (kyi < 32) ? kyi : (192 + kyi);  // 224..255
    float sd_, cd_;
    sincosf((float)ky * (PI_F / 128.f), &sd_, &cd_);
    float cd = cd_, sd = -sd_;    // e^{-i*2pi*ky/256}
    float cr = 1.f, ci = 0.f, ar = 0.f, ai = 0.f;
#pragma unroll 4
    for (int y = 0; y < NH; ++y) {
      float2 v = t[y * NM + kx];
      ar += v.x * cr - v.y * ci;
      ai += v.x * ci + v.y * cr;
      float nr = cr * cd - ci * sd; ci = ci * cd + cr * sd; cr = nr;
    }
    dst[kyi * NM + kx] = make_float2(ar, ai);
  }
}

// ---- spectral channel mix: per mode (kyi,kx): out[b,o] = sum_i X[b,i] * W[i,o]
__global__ __launch_bounds__(512) void k_spec(const float2* __restrict__ Xft,
                                              const float* __restrict__ w1r,
                                              const float* __restrict__ w1i,
                                              const float* __restrict__ w2r,
                                              const float* __restrict__ w2i,
                                              float2* __restrict__ S) {
  int b = blockIdx.y;
  int och = blockIdx.x & 3;
  int kyi = blockIdx.x >> 2;      // 0..63
  __shared__ float2 xs[NC * NM];  // 16 KB
  for (int idx = threadIdx.x; idx < NC * NM; idx += 512) {
    int i = idx >> 5, kx = idx & 31;
    xs[idx] = Xft[(((size_t)b * NC + i) * NKY + kyi) * NM + kx];
  }
  __syncthreads();
  int kx = threadIdx.x & 31;
  int ol = threadIdx.x >> 5;      // 0..15
  int o = och * 16 + ol;
  int kym = kyi & 31;
  const float* wr = (kyi < 32) ? w1r : w2r;
  const float* wi = (kyi < 32) ? w1i : w2i;
  size_t wb = ((size_t)o * NM + kym) * NM + kx;   // [i][o][ky][kx], i-stride 65536
  float ar = 0.f, ai = 0.f;
#pragma unroll 4
  for (int i = 0; i < NC; ++i) {
    float2 xv = xs[i * NM + kx];
    float wrv = wr[wb + (size_t)i * 65536];
    float wiv = wi[wb + (size_t)i * 65536];
    ar += xv.x * wrv - xv.y * wiv;
    ai += xv.x * wiv + xv.y * wrv;
  }
  S[(((size_t)b * NC + o) * NKY + kyi) * NM + kx] = make_float2(ar, ai);
}

// ---- fused inverse y-DFT + inverse x-c2r per (b,c); scale 1/65536 folded here
__global__ __launch_bounds__(256) void k_iyx(const float2* __restrict__ S,
                                             const float2* __restrict__ tab,
                                             float* __restrict__ x1) {
  int bc = blockIdx.y * NC + blockIdx.x;
  __shared__ float2 ss[NKY * NM];  // 16 KB
  __shared__ float2 t2[NH * NM];   // 64 KB
  const float2* src = S + (size_t)bc * (NKY * NM);
  for (int i = threadIdx.x; i < NKY * NM; i += 256) ss[i] = src[i];
  __syncthreads();
  {
    int kx = threadIdx.x & 31;
    int yl = threadIdx.x >> 5;     // 0..7
    int ybase = yl * 32;
    float ar[32], ai[32];
#pragma unroll
    for (int j = 0; j < 32; ++j) { ar[j] = 0.f; ai[j] = 0.f; }
    for (int kyi = 0; kyi < NKY; ++kyi) {
      float2 sv = ss[kyi * NM + kx];
      int ky = (kyi < 32) ? kyi : (192 + kyi);
      int a0 = (ky * ybase) & 255;
      float c0, s0, cd, sd;
      sincosf((float)a0 * (PI_F / 128.f), &s0, &c0);
      sincosf((float)ky * (PI_F / 128.f), &sd, &cd);   // e^{+i*2pi*ky/256}
      float cr = c0, ci = s0;
#pragma unroll
      for (int j = 0; j < 32; ++j) {
        ar[j] += sv.x * cr - sv.y * ci;
        ai[j] += sv.x * ci + sv.y * cr;
        float nr = cr * cd - ci * sd; ci = ci * cd + cr * sd; cr = nr;
      }
    }
#pragma unroll
    for (int j = 0; j < 32; ++j)
      t2[(ybase + j) * NM + kx] = make_float2(ar[j], ai[j]);
  }
  __syncthreads();
  // phase 2: thread = x column
  int xx = threadIdx.x;
  float ck[31], sk[31];
#pragma unroll
  for (int k = 1; k < 32; ++k) {
    float2 tv = tab[k * 256 + xx];
    ck[k - 1] = tv.x; sk[k - 1] = tv.y;
  }
  float* dst = x1 + (size_t)bc * HW;
  for (int y = 0; y < NH; ++y) {
    const float2* row = t2 + y * NM;
    float acc = 0.5f * row[0].x;   // Im of DC bin ignored (pocketfft c2r semantics)
#pragma unroll
    for (int k = 1; k < 32; ++k) {
      float2 v = row[k];
      acc += v.x * ck[k - 1] - v.y * sk[k - 1];
    }
    dst[y * NW + xx] = acc * (2.0f / 65536.0f);
  }
}

// ---- MLP conv1 + exact GELU, in-place [b,c,y,x] -> [b,m,y,x]
__global__ __launch_bounds__(256) void k_mlp1(float* __restrict__ xm,
                                              const float* __restrict__ w,
                                              const float* __restrict__ bias) {
  int b = blockIdx.y;
  int yx = blockIdx.x * 256 + threadIdx.x;
  float* base = xm + (size_t)b * NC * HW + yx;
  float hv[NC];
#pragma unroll
  for (int c = 0; c < NC; ++c) hv[c] = base[(size_t)c * HW];
  for (int m = 0; m < NC; ++m) {
    const float* wrow = w + m * NC;
    float acc = bias[m];
#pragma unroll
    for (int c = 0; c < NC; ++c) acc += hv[c] * wrow[c];
    base[(size_t)m * HW] = gelu_f(acc);
  }
}

// ---- MLP conv2 + skip conv + add (+ GELU), h updated in-place
__global__ __launch_bounds__(256) void k_mlp2skip(const float* __restrict__ mid,
                                                  float* __restrict__ h,
                                                  const float* __restrict__ m2wT,
                                                  const float* __restrict__ m2b,
                                                  const float* __restrict__ skwT,
                                                  const float* __restrict__ skb,
                                                  int do_gelu) {
  int b = blockIdx.y;
  int yx = blockIdx.x * 256 + threadIdx.x;
  const float* mb = mid + (size_t)b * NC * HW + yx;
  float* hb = h + (size_t)b * NC * HW + yx;
  float acc[NC];
#pragma unroll
  for (int o = 0; o < NC; ++o) acc[o] = m2b[o] + skb[o];
  for (int m = 0; m < NC; ++m) {
    float v = mb[(size_t)m * HW];
    const float* wr = m2wT + m * NC;
#pragma unroll
    for (int o = 0; o < NC; ++o) acc[o] += v * wr[o];
  }
  for (int c = 0; c < NC; ++c) {
    float v = hb[(size_t)c * HW];
    const float* wr = skwT + c * NC;
#pragma unroll
    for (int o = 0; o < NC; ++o) acc[o] += v * wr[o];
  }
  if (do_gelu) {
#pragma unroll
    for (int o = 0; o < NC; ++o) acc[o] = gelu_f(acc[o]);
  }
#pragma unroll
  for (int o = 0; o < NC; ++o) hb[(size_t)o * HW] = acc[o];
}

// ---- projection: out = q2 . gelu(q1 . h + q1b) + q2b, fused (no 1GB intermediate)
__global__ __launch_bounds__(256) void k_proj(const float* __restrict__ h,
                                              const float* __restrict__ q1w,
                                              const float* __restrict__ q1b,
                                              const float* __restrict__ q2w,
                                              const float* __restrict__ q2b,
                                              float* __restrict__ out) {
  int b = blockIdx.y;
  int yx = blockIdx.x * 256 + threadIdx.x;
  const float* hb = h + (size_t)b * NC * HW + yx;
  float hv[NC];
#pragma unroll
  for (int c = 0; c < NC; ++c) hv[c] = hb[(size_t)c * HW];
  float acc = q2b[0];
  for (int m = 0; m < 256; ++m) {
    const float* wr = q1w + m * NC;
    float s = q1b[m];
#pragma unroll
    for (int c = 0; c < NC; ++c) s += hv[c] * wr[c];
    acc += gelu_f(s) * q2w[m];
  }
  out[(size_t)b * HW + yx] = acc;
}

extern "C" void kernel_launch(void* const* d_in, const int* in_sizes, int n_in,
                              void* d_out, int out_size, void* d_ws, size_t ws_size,
                              hipStream_t stream) {
  const float* x    = (const float*)d_in[0];
  const float* p_w  = (const float*)d_in[1];
  const float* p_b  = (const float*)d_in[2];
  const float* sw1r = (const float*)d_in[3];
  const float* sw1i = (const float*)d_in[4];
  const float* sw2r = (const float*)d_in[5];
  const float* sw2i = (const float*)d_in[6];
  const float* m1w  = (const float*)d_in[7];
  const float* m1b  = (const float*)d_in[8];
  const float* m2w  = (const float*)d_in[9];
  const float* m2b  = (const float*)d_in[10];
  const float* skw  = (const float*)d_in[11];
  const float* skb  = (const float*)d_in[12];
  const float* q1w  = (const float*)d_in[13];
  const float* q1b  = (const float*)d_in[14];
  const float* q2w  = (const float*)d_in[15];
  const float* q2b  = (const float*)d_in[16];

  // Adaptive batch chunking: per-batch live set is A(16MB) + Cbuf(16MB) + S(1MB).
  // T1 (4MB/b) and Xft (1MB/b) alias into dead regions of Cbuf; S must be
  // separate (k_iyx reads S while writing all of Cbuf). Tables: 192 KB.
  const size_t MB = 1024ULL * 1024ULL;
  const size_t small = 3 * 65536ULL;
  int g = 16;
  while (g > 1 && (size_t)g * 33 * MB + small > ws_size) g >>= 1;
  if ((size_t)g * 33 * MB + small > ws_size) return;  // cannot run at all

  char* wsb = (char*)d_ws;
  float2* tab  = (float2*)wsb;                    // 64 KB (32*256 float2)
  float*  m2wT = (float*)(wsb + 65536);           // 64 KB
  float*  skwT = (float*)(wsb + 131072);          // 64 KB
  char* base = wsb + small;
  float*  A    = (float*)base;                            // g*16 MB  (h)
  float*  Cbuf = (float*)(base + (size_t)g * 16 * MB);    // g*16 MB  (x1/mid)
  float2* T1   = (float2*)Cbuf;                           // alias: g*4 MB
  float2* Xft  = (float2*)(base + (size_t)g * 20 * MB);   // alias: g*1 MB
  float2* S    = (float2*)(base + (size_t)g * 32 * MB);   // g*1 MB (separate!)

  k_tab<<<32, 256, 0, stream>>>(tab);
  k_transpose<<<64, 256, 0, stream>>>(m2w, m2wT);
  k_transpose<<<64, 256, 0, stream>>>(skw, skwT);

  for (int b0 = 0; b0 < 16; b0 += g) {
    const float* xc = x + (size_t)b0 * HW;
    float* outc = (float*)d_out + (size_t)b0 * HW;
    k_lift<<<dim3(256, g), 256, 0, stream>>>(xc, p_w, p_b, A);
    for (int l = 0; l < 4; ++l) {
      const float* w1r = sw1r + (size_t)l * 4194304;
      const float* w1i = sw1i + (size_t)l * 4194304;
      const float* w2r = sw2r + (size_t)l * 4194304;
      const float* w2i = sw2i + (size_t)l * 4194304;
      k_fx<<<dim3(1024, g), 256, 0, stream>>>(A, T1);
      k_fy<<<dim3(64, g), 512, 0, stream>>>(T1, Xft);
      k_spec<<<dim3(256, g), 512, 0, stream>>>(Xft, w1r, w1i, w2r, w2i, S);
      k_iyx<<<dim3(64, g), 256, 0, stream>>>(S, tab, Cbuf);
      k_mlp1<<<dim3(256, g), 256, 0, stream>>>(Cbuf, m1w + l * 4096, m1b + l * 64);
      k_mlp2skip<<<dim3(256, g), 256, 0, stream>>>(Cbuf, A, m2wT + l * 4096, m2b + l * 64,
                                                   skwT + l * 4096, skb + l * 64, (l < 3) ? 1 : 0);
    }
    k_proj<<<dim3(256, g), 256, 0, stream>>>(A, q1w, q1b, q2w, q2b, outc);
  }
}

// Round 4
// 7030.333 us; speedup vs baseline: 1.3738x; 1.3738x over previous
//
#include <hip/hip_runtime.h>
#include <math.h>

#define NC 64
#define NH 256
#define NW 256
#define NM 32
#define NKY 64
#define HW 65536

typedef short bfrag __attribute__((ext_vector_type(8)));   // 8 bf16 (4 VGPR)
typedef float facc  __attribute__((ext_vector_type(4)));   // 4 f32 acc
#define MFMA(a,b,c) __builtin_amdgcn_mfma_f32_16x16x32_bf16(a,b,c,0,0,0)

static constexpr float PI_F = 3.14159265358979323846f;

__device__ __forceinline__ unsigned short f2b(float f) {  // f32 -> bf16 RNE
  unsigned b = __float_as_uint(f);
  return (unsigned short)((b + 0x7FFFu + ((b >> 16) & 1u)) >> 16);
}
__device__ __forceinline__ float b2f(unsigned short h) {
  return __uint_as_float((unsigned)h << 16);
}

// branchless erf-based exact GELU (A&S 7.1.26, |err| < 1.5e-7)
__device__ __forceinline__ float gelu_f(float x) {
  float z = fabsf(x) * 0.70710678118654752f;
  float t = 1.0f / (1.0f + 0.3275911f * z);
  float e = __expf(-z * z);
  float p = t * (0.254829592f + t * (-0.284496736f + t * (1.421413741f +
            t * (-1.453152027f + t * 1.061405429f))));
  float er = copysignf(1.0f - p * e, x);
  return 0.5f * x * (1.0f + er);
}

// ---- init: cos/sin table for inverse-x DFT
__global__ void k_tab(float2* __restrict__ tab) {
  int i = blockIdx.x * 256 + threadIdx.x;   // 32*256
  int k = i >> 8, x = i & 255;
  int a = (k * x) & 255;
  float s, c;
  sincosf((float)a * (PI_F / 128.f), &s, &c);
  tab[i] = make_float2(c, s);
}

// ---- init: f32 -> bf16 hi/lo split
__global__ void k_cvt2(const float* __restrict__ src, unsigned short* __restrict__ hi,
                       unsigned short* __restrict__ lo, int n) {
  int i = blockIdx.x * 256 + threadIdx.x;
  if (i < n) {
    float v = src[i];
    unsigned short h = f2b(v);
    hi[i] = h;
    lo[i] = f2b(v - b2f(h));
  }
}

// ---- lift
__global__ __launch_bounds__(256) void k_lift(const float* __restrict__ x,
                                              const float* __restrict__ pw,
                                              const float* __restrict__ pb,
                                              float* __restrict__ h) {
  int b = blockIdx.y;
  int yx = blockIdx.x * 256 + threadIdx.x;
  float v = x[(size_t)b * HW + yx];
  float* hp = h + (size_t)b * NC * HW + yx;
  for (int c = 0; c < NC; ++c) hp[(size_t)c * HW] = v * pw[c] + pb[c];
}

// ---- forward x-DFT (real -> 32 complex modes), f32 phase recurrence
__global__ __launch_bounds__(256) void k_fx(const float* __restrict__ h, float2* __restrict__ T1) {
  int ytile = blockIdx.x & 15;
  int c = blockIdx.x >> 4;
  int bc = blockIdx.y * NC + c;
  const float* src = h + (size_t)bc * HW + ytile * (16 * NW);
  __shared__ float rows[16 * NW];
  for (int i = threadIdx.x; i < 16 * NW; i += 256) rows[i] = src[i];
  __syncthreads();
  int kx = threadIdx.x & 31;
  int y0 = threadIdx.x >> 5;
  float sd_, cd_;
  sincosf((float)kx * (PI_F / 128.f), &sd_, &cd_);
  float cd = cd_, sd = -sd_;
  const float* r0 = rows + y0 * NW;
  const float* r1 = rows + (y0 + 8) * NW;
  float cr = 1.f, ci = 0.f;
  float a0r = 0.f, a0i = 0.f, a1r = 0.f, a1i = 0.f;
#pragma unroll 4
  for (int xx = 0; xx < NW; ++xx) {
    float v0 = r0[xx], v1 = r1[xx];
    a0r += v0 * cr; a0i += v0 * ci;
    a1r += v1 * cr; a1i += v1 * ci;
    float nr = cr * cd - ci * sd; ci = ci * cd + cr * sd; cr = nr;
  }
  int ybase = ytile * 16;
  float2* dst = T1 + (size_t)bc * NH * NM;
  dst[(ybase + y0) * NM + kx]     = make_float2(a0r, a0i);
  dst[(ybase + y0 + 8) * NM + kx] = make_float2(a1r, a1i);
}

// ---- forward y-DFT (256 complex -> 64 kept modes)
__global__ __launch_bounds__(512) void k_fy(const float2* __restrict__ T1, float2* __restrict__ Xft) {
  int bc = blockIdx.y * NC + blockIdx.x;
  __shared__ float2 t[NH * NM];   // 64 KB
  const float2* src = T1 + (size_t)bc * (NH * NM);
  for (int i = threadIdx.x; i < NH * NM; i += 512) t[i] = src[i];
  __syncthreads();
  int kx = threadIdx.x & 31;
  int kyl = threadIdx.x >> 5;
  float2* dst = Xft + (size_t)bc * (NKY * NM);
  for (int p = 0; p < 4; ++p) {
    int kyi = p * 16 + kyl;
    int ky = (kyi < 32) ? kyi : (192 + kyi);
    float sd_, cd_;
    sincosf((float)ky * (PI_F / 128.f), &sd_, &cd_);
    float cd = cd_, sd = -sd_;
    float cr = 1.f, ci = 0.f, ar = 0.f, ai = 0.f;
#pragma unroll 4
    for (int y = 0; y < NH; ++y) {
      float2 v = t[y * NM + kx];
      ar += v.x * cr - v.y * ci;
      ai += v.x * ci + v.y * cr;
      float nr = cr * cd - ci * sd; ci = ci * cd + cr * sd; cr = nr;
    }
    dst[kyi * NM + kx] = make_float2(ar, ai);
  }
}

// ---- spectral channel mix (f32)
__global__ __launch_bounds__(512) void k_spec(const float2* __restrict__ Xft,
                                              const float* __restrict__ w1r,
                                              const float* __restrict__ w1i,
                                              const float* __restrict__ w2r,
                                              const float* __restrict__ w2i,
                                              float2* __restrict__ S) {
  int b = blockIdx.y;
  int och = blockIdx.x & 3;
  int kyi = blockIdx.x >> 2;
  __shared__ float2 xs[NC * NM];
  for (int idx = threadIdx.x; idx < NC * NM; idx += 512) {
    int i = idx >> 5, kx = idx & 31;
    xs[idx] = Xft[(((size_t)b * NC + i) * NKY + kyi) * NM + kx];
  }
  __syncthreads();
  int kx = threadIdx.x & 31;
  int ol = threadIdx.x >> 5;
  int o = och * 16 + ol;
  int kym = kyi & 31;
  const float* wr = (kyi < 32) ? w1r : w2r;
  const float* wi = (kyi < 32) ? w1i : w2i;
  size_t wb = ((size_t)o * NM + kym) * NM + kx;
  float ar = 0.f, ai = 0.f;
#pragma unroll 4
  for (int i = 0; i < NC; ++i) {
    float2 xv = xs[i * NM + kx];
    float wrv = wr[wb + (size_t)i * 65536];
    float wiv = wi[wb + (size_t)i * 65536];
    ar += xv.x * wrv - xv.y * wiv;
    ai += xv.x * wiv + xv.y * wrv;
  }
  S[(((size_t)b * NC + o) * NKY + kyi) * NM + kx] = make_float2(ar, ai);
}

// ---- fused inverse y-DFT + inverse x-c2r; writes x1 as bf16 PAIR (hi/lo planes)
__global__ __launch_bounds__(256) void k_iyx(const float2* __restrict__ S,
                                             const float2* __restrict__ tab,
                                             unsigned short* __restrict__ x1h,
                                             unsigned short* __restrict__ x1l) {
  int bc = blockIdx.y * NC + blockIdx.x;
  __shared__ float2 ss[NKY * NM];
  __shared__ float2 t2[NH * NM];
  const float2* src = S + (size_t)bc * (NKY * NM);
  for (int i = threadIdx.x; i < NKY * NM; i += 256) ss[i] = src[i];
  __syncthreads();
  {
    int kx = threadIdx.x & 31;
    int yl = threadIdx.x >> 5;
    int ybase = yl * 32;
    float ar[32], ai[32];
#pragma unroll
    for (int j = 0; j < 32; ++j) { ar[j] = 0.f; ai[j] = 0.f; }
    for (int kyi = 0; kyi < NKY; ++kyi) {
      float2 sv = ss[kyi * NM + kx];
      int ky = (kyi < 32) ? kyi : (192 + kyi);
      int a0 = (ky * ybase) & 255;
      float c0, s0, cd, sd;
      sincosf((float)a0 * (PI_F / 128.f), &s0, &c0);
      sincosf((float)ky * (PI_F / 128.f), &sd, &cd);
      float cr = c0, ci = s0;
#pragma unroll
      for (int j = 0; j < 32; ++j) {
        ar[j] += sv.x * cr - sv.y * ci;
        ai[j] += sv.x * ci + sv.y * cr;
        float nr = cr * cd - ci * sd; ci = ci * cd + cr * sd; cr = nr;
      }
    }
#pragma unroll
    for (int j = 0; j < 32; ++j)
      t2[(ybase + j) * NM + kx] = make_float2(ar[j], ai[j]);
  }
  __syncthreads();
  int xx = threadIdx.x;
  float ck[31], sk[31];
#pragma unroll
  for (int k = 1; k < 32; ++k) {
    float2 tv = tab[k * 256 + xx];
    ck[k - 1] = tv.x; sk[k - 1] = tv.y;
  }
  unsigned short* dh = x1h + (size_t)bc * HW;
  unsigned short* dl = x1l + (size_t)bc * HW;
  for (int y = 0; y < NH; ++y) {
    const float2* row = t2 + y * NM;
    float acc = 0.5f * row[0].x;
#pragma unroll
    for (int k = 1; k < 32; ++k) {
      float2 v = row[k];
      acc += v.x * ck[k - 1] - v.y * sk[k - 1];
    }
    float v = acc * (2.0f / 65536.0f);
    unsigned short hi = f2b(v);
    dh[y * NW + xx] = hi;
    dl[y * NW + xx] = f2b(v - b2f(hi));
  }
}

// ---- MLP conv1 + GELU via split-bf16 MFMA; in-place x1 pair -> mid pair
__global__ __launch_bounds__(256) void k_mlp1s(unsigned short* __restrict__ x1h,
                                               unsigned short* __restrict__ x1l,
                                               const unsigned short* __restrict__ w1h,
                                               const unsigned short* __restrict__ w1l,
                                               const float* __restrict__ b1p) {
  __shared__ unsigned short whs[64 * 72], wls[64 * 72];   // 18.4 KB
  int tid = threadIdx.x;
  for (int i = tid; i < 64 * 64; i += 256) {
    int r = i >> 6, c = i & 63;
    whs[r * 72 + c] = w1h[i];
    wls[r * 72 + c] = w1l[i];
  }
  int wv = tid >> 6, ln = tid & 63, g16 = ln >> 4, l15 = ln & 15;
  int b = blockIdx.y;
  unsigned short* xh = x1h + (size_t)b * NC * HW;
  unsigned short* xl = x1l + (size_t)b * NC * HW;
  float b1v[4][4];
#pragma unroll
  for (int mf = 0; mf < 4; ++mf)
#pragma unroll
    for (int r = 0; r < 4; ++r) b1v[mf][r] = b1p[16 * mf + 4 * g16 + r];
  __syncthreads();
  for (int t = 0; t < 4; ++t) {
    int pxb = (blockIdx.x * 4 + t) * 128 + wv * 32;
    facc a1[4][2];
#pragma unroll
    for (int mf = 0; mf < 4; ++mf)
#pragma unroll
      for (int pf = 0; pf < 2; ++pf) {
        facc z; z[0] = b1v[mf][0]; z[1] = b1v[mf][1]; z[2] = b1v[mf][2]; z[3] = b1v[mf][3];
        a1[mf][pf] = z;
      }
#pragma unroll
    for (int ks = 0; ks < 2; ++ks) {
      bfrag xhb[2], xlb[2];
#pragma unroll
      for (int pf = 0; pf < 2; ++pf) {
        int px = pxb + pf * 16 + l15;
#pragma unroll
        for (int j = 0; j < 8; ++j) {
          int c = g16 * 8 + j + 32 * ks;
          xhb[pf][j] = (short)xh[(size_t)c * HW + px];
          xlb[pf][j] = (short)xl[(size_t)c * HW + px];
        }
      }
#pragma unroll
      for (int mf = 0; mf < 4; ++mf) {
        bfrag wh = *(const bfrag*)(whs + (16 * mf + l15) * 72 + g16 * 8 + 32 * ks);
        bfrag wl = *(const bfrag*)(wls + (16 * mf + l15) * 72 + g16 * 8 + 32 * ks);
#pragma unroll
        for (int pf = 0; pf < 2; ++pf) {
          a1[mf][pf] = MFMA(wh, xhb[pf], a1[mf][pf]);
          a1[mf][pf] = MFMA(wh, xlb[pf], a1[mf][pf]);
          a1[mf][pf] = MFMA(wl, xhb[pf], a1[mf][pf]);
        }
      }
    }
#pragma unroll
    for (int mf = 0; mf < 4; ++mf)
#pragma unroll
      for (int pf = 0; pf < 2; ++pf) {
        int px = pxb + pf * 16 + l15;
#pragma unroll
        for (int r = 0; r < 4; ++r) {
          float v = gelu_f(a1[mf][pf][r]);
          unsigned short hi = f2b(v);
          size_t idx = (size_t)(16 * mf + 4 * g16 + r) * HW + px;
          xh[idx] = hi;
          xl[idx] = f2b(v - b2f(hi));
        }
      }
  }
}

// ---- conv2 + skip + add (+GELU) via split-bf16 MFMA; h (f32) updated in place
__global__ __launch_bounds__(256) void k_mix2(const unsigned short* __restrict__ midh,
                                              const unsigned short* __restrict__ midl,
                                              float* __restrict__ h,
                                              const unsigned short* __restrict__ w2h,
                                              const unsigned short* __restrict__ w2l,
                                              const unsigned short* __restrict__ skh,
                                              const unsigned short* __restrict__ skl,
                                              const float* __restrict__ b2p,
                                              const float* __restrict__ skbp,
                                              int do_gelu) {
  __shared__ unsigned short w2hs[64 * 72], w2ls[64 * 72], skhs[64 * 72], skls[64 * 72]; // 36.9 KB
  int tid = threadIdx.x;
  for (int i = tid; i < 64 * 64; i += 256) {
    int r = i >> 6, c = i & 63;
    w2hs[r * 72 + c] = w2h[i];
    w2ls[r * 72 + c] = w2l[i];
    skhs[r * 72 + c] = skh[i];
    skls[r * 72 + c] = skl[i];
  }
  int wv = tid >> 6, ln = tid & 63, g16 = ln >> 4, l15 = ln & 15;
  int b = blockIdx.y;
  const unsigned short* mh = midh + (size_t)b * NC * HW;
  const unsigned short* ml = midl + (size_t)b * NC * HW;
  float* hb = h + (size_t)b * NC * HW;
  float b2v[4][4];
#pragma unroll
  for (int mf = 0; mf < 4; ++mf)
#pragma unroll
    for (int r = 0; r < 4; ++r) {
      int o = 16 * mf + 4 * g16 + r;
      b2v[mf][r] = b2p[o] + skbp[o];
    }
  __syncthreads();
  for (int t = 0; t < 4; ++t) {
    int pxb = (blockIdx.x * 4 + t) * 128 + wv * 32;
    facc a2[4][2];
#pragma unroll
    for (int mf = 0; mf < 4; ++mf)
#pragma unroll
      for (int pf = 0; pf < 2; ++pf) {
        facc z; z[0] = b2v[mf][0]; z[1] = b2v[mf][1]; z[2] = b2v[mf][2]; z[3] = b2v[mf][3];
        a2[mf][pf] = z;
      }
#pragma unroll
    for (int ks = 0; ks < 2; ++ks) {
      bfrag mhb[2], mlb[2], hhb[2], hlb[2];
#pragma unroll
      for (int pf = 0; pf < 2; ++pf) {
        int px = pxb + pf * 16 + l15;
#pragma unroll
        for (int j = 0; j < 8; ++j) {
          int c = g16 * 8 + j + 32 * ks;
          mhb[pf][j] = (short)mh[(size_t)c * HW + px];
          mlb[pf][j] = (short)ml[(size_t)c * HW + px];
          float v = hb[(size_t)c * HW + px];
          unsigned short hi = f2b(v);
          hhb[pf][j] = (short)hi;
          hlb[pf][j] = (short)f2b(v - b2f(hi));
        }
      }
#pragma unroll
      for (int mf = 0; mf < 4; ++mf) {
        bfrag w2hf = *(const bfrag*)(w2hs + (16 * mf + l15) * 72 + g16 * 8 + 32 * ks);
        bfrag w2lf = *(const bfrag*)(w2ls + (16 * mf + l15) * 72 + g16 * 8 + 32 * ks);
        bfrag skhf = *(const bfrag*)(skhs + (16 * mf + l15) * 72 + g16 * 8 + 32 * ks);
        bfrag sklf = *(const bfrag*)(skls + (16 * mf + l15) * 72 + g16 * 8 + 32 * ks);
#pragma unroll
        for (int pf = 0; pf < 2; ++pf) {
          a2[mf][pf] = MFMA(w2hf, mhb[pf], a2[mf][pf]);
          a2[mf][pf] = MFMA(w2hf, mlb[pf], a2[mf][pf]);
          a2[mf][pf] = MFMA(w2lf, mhb[pf], a2[mf][pf]);
          a2[mf][pf] = MFMA(skhf, hhb[pf], a2[mf][pf]);
          a2[mf][pf] = MFMA(skhf, hlb[pf], a2[mf][pf]);
          a2[mf][pf] = MFMA(sklf, hhb[pf], a2[mf][pf]);
        }
      }
    }
#pragma unroll
    for (int mf = 0; mf < 4; ++mf)
#pragma unroll
      for (int pf = 0; pf < 2; ++pf) {
        facc v = a2[mf][pf];
        if (do_gelu) {
          v[0] = gelu_f(v[0]); v[1] = gelu_f(v[1]);
          v[2] = gelu_f(v[2]); v[3] = gelu_f(v[3]);
        }
        int px = pxb + pf * 16 + l15;
#pragma unroll
        for (int r = 0; r < 4; ++r)
          hb[(size_t)(16 * mf + 4 * g16 + r) * HW + px] = v[r];
      }
  }
}

// ---- projection via split-bf16 MFMA; q1 fragments in registers
__global__ __launch_bounds__(256) void k_proj2s(const float* __restrict__ h,
                                                const unsigned short* __restrict__ q1h,
                                                const unsigned short* __restrict__ q1l,
                                                const float* __restrict__ q1bp,
                                                const float* __restrict__ q2wp,
                                                const float* __restrict__ q2bp,
                                                float* __restrict__ out) {
  __shared__ float part[4][16];
  int tid = threadIdx.x;
  int wv = tid >> 6, ln = tid & 63, g16 = ln >> 4, l15 = ln & 15;
  int b = blockIdx.y;
  const float* hb = h + (size_t)b * NC * HW;
  bfrag qh[4][2], ql[4][2];
#pragma unroll
  for (int mf = 0; mf < 4; ++mf)
#pragma unroll
    for (int ks = 0; ks < 2; ++ks) {
      int row = 64 * wv + 16 * mf + l15;
      size_t base = (size_t)row * 64 + g16 * 8 + 32 * ks;
      qh[mf][ks] = *(const bfrag*)(q1h + base);
      ql[mf][ks] = *(const bfrag*)(q1l + base);
    }
  float bq[4][4], qv[4][4];
#pragma unroll
  for (int mf = 0; mf < 4; ++mf)
#pragma unroll
    for (int r = 0; r < 4; ++r) {
      int row = 64 * wv + 16 * mf + 4 * g16 + r;
      bq[mf][r] = q1bp[row];
      qv[mf][r] = q2wp[row];
    }
  float q2bias = q2bp[0];
  for (int t = 0; t < 16; ++t) {
    int px0 = blockIdx.x * 256 + t * 16;
    facc acc[4];
#pragma unroll
    for (int mf = 0; mf < 4; ++mf) {
      facc z; z[0] = bq[mf][0]; z[1] = bq[mf][1]; z[2] = bq[mf][2]; z[3] = bq[mf][3];
      acc[mf] = z;
    }
#pragma unroll
    for (int ks = 0; ks < 2; ++ks) {
      bfrag hh, hl;
#pragma unroll
      for (int j = 0; j < 8; ++j) {
        int c = g16 * 8 + j + 32 * ks;
        float v = hb[(size_t)c * HW + px0 + l15];
        unsigned short hi = f2b(v);
        hh[j] = (short)hi;
        hl[j] = (short)f2b(v - b2f(hi));
      }
#pragma unroll
      for (int mf = 0; mf < 4; ++mf) {
        acc[mf] = MFMA(qh[mf][ks], hh, acc[mf]);
        acc[mf] = MFMA(qh[mf][ks], hl, acc[mf]);
        acc[mf] = MFMA(ql[mf][ks], hh, acc[mf]);
      }
    }
    float partial = 0.f;
#pragma unroll
    for (int mf = 0; mf < 4; ++mf)
#pragma unroll
      for (int r = 0; r < 4; ++r)
        partial += gelu_f(acc[mf][r]) * qv[mf][r];
    partial += __shfl_xor(partial, 16);
    partial += __shfl_xor(partial, 32);
    if (ln < 16) part[wv][l15] = partial;
    __syncthreads();
    if (tid < 16)
      out[(size_t)b * HW + px0 + tid] =
          part[0][tid] + part[1][tid] + part[2][tid] + part[3][tid] + q2bias;
    __syncthreads();
  }
}

extern "C" void kernel_launch(void* const* d_in, const int* in_sizes, int n_in,
                              void* d_out, int out_size, void* d_ws, size_t ws_size,
                              hipStream_t stream) {
  const float* x    = (const float*)d_in[0];
  const float* p_w  = (const float*)d_in[1];
  const float* p_b  = (const float*)d_in[2];
  const float* sw1r = (const float*)d_in[3];
  const float* sw1i = (const float*)d_in[4];
  const float* sw2r = (const float*)d_in[5];
  const float* sw2i = (const float*)d_in[6];
  const float* m1w  = (const float*)d_in[7];
  const float* m1b  = (const float*)d_in[8];
  const float* m2w  = (const float*)d_in[9];
  const float* m2b  = (const float*)d_in[10];
  const float* skw  = (const float*)d_in[11];
  const float* skb  = (const float*)d_in[12];
  const float* q1w  = (const float*)d_in[13];
  const float* q1b  = (const float*)d_in[14];
  const float* q2w  = (const float*)d_in[15];
  const float* q2b  = (const float*)d_in[16];

  // Per-batch live set: A (h f32, 16MB) + X (x1/mid bf16 pair, 16MB: hi plane
  // g*8MB then lo plane g*8MB; T1 4MB/b + Xft 1MB/b alias into X's dead
  // spectral-phase region) + S (1MB). Tables+split weights: 320KB.
  const size_t MB = 1048576ULL;
  const size_t TBL = 327680ULL;
  int g = 16;
  while (g > 1 && (size_t)g * 33 * MB + TBL > ws_size) g >>= 1;
  if ((size_t)g * 33 * MB + TBL > ws_size) return;

  char* wsb = (char*)d_ws;
  float2* tab = (float2*)wsb;                               // 64 KB
  unsigned short* m1h = (unsigned short*)(wsb + 65536);     // 32 KB each
  unsigned short* m1l = (unsigned short*)(wsb + 98304);
  unsigned short* m2h = (unsigned short*)(wsb + 131072);
  unsigned short* m2l = (unsigned short*)(wsb + 163840);
  unsigned short* skh = (unsigned short*)(wsb + 196608);
  unsigned short* skl = (unsigned short*)(wsb + 229376);
  unsigned short* q1h = (unsigned short*)(wsb + 262144);
  unsigned short* q1l = (unsigned short*)(wsb + 294912);
  char* base = wsb + TBL;
  float* A = (float*)base;                                  // g*16 MB (h master, f32)
  char* X = base + (size_t)g * 16 * MB;                     // g*16 MB
  unsigned short* x1h = (unsigned short*)X;                 // g*8 MB
  unsigned short* x1l = (unsigned short*)(X + (size_t)g * 8 * MB);  // g*8 MB
  float2* T1  = (float2*)X;                                 // alias g*4 MB
  float2* Xft = (float2*)(X + (size_t)g * 4 * MB);          // alias g*1 MB
  float2* S   = (float2*)(base + (size_t)g * 32 * MB);      // g*1 MB (separate)

  k_tab<<<32, 256, 0, stream>>>(tab);
  k_cvt2<<<64, 256, 0, stream>>>(m1w, m1h, m1l, 16384);
  k_cvt2<<<64, 256, 0, stream>>>(m2w, m2h, m2l, 16384);
  k_cvt2<<<64, 256, 0, stream>>>(skw, skh, skl, 16384);
  k_cvt2<<<64, 256, 0, stream>>>(q1w, q1h, q1l, 16384);

  for (int b0 = 0; b0 < 16; b0 += g) {
    k_lift<<<dim3(256, g), 256, 0, stream>>>(x + (size_t)b0 * HW, p_w, p_b, A);
    for (int l = 0; l < 4; ++l) {
      k_fx<<<dim3(1024, g), 256, 0, stream>>>(A, T1);
      k_fy<<<dim3(64, g), 512, 0, stream>>>(T1, Xft);
      k_spec<<<dim3(256, g), 512, 0, stream>>>(Xft, sw1r + (size_t)l * 4194304,
                                               sw1i + (size_t)l * 4194304,
                                               sw2r + (size_t)l * 4194304,
                                               sw2i + (size_t)l * 4194304, S);
      k_iyx<<<dim3(64, g), 256, 0, stream>>>(S, tab, x1h, x1l);
      k_mlp1s<<<dim3(128, g), 256, 0, stream>>>(x1h, x1l, m1h + l * 4096, m1l + l * 4096,
                                                m1b + l * 64);
      k_mix2<<<dim3(128, g), 256, 0, stream>>>(x1h, x1l, A, m2h + l * 4096, m2l + l * 4096,
                                               skh + l * 4096, skl + l * 4096,
                                               m2b + l * 64, skb + l * 64, (l < 3) ? 1 : 0);
    }
    k_proj2s<<<dim3(256, g), 256, 0, stream>>>(A, q1h, q1l, q1b, q2w, q2b,
                                               (float*)d_out + (size_t)b0 * HW);
  }
}

// Round 5
// 4189.188 us; speedup vs baseline: 2.3055x; 1.6782x over previous
//
#include <hip/hip_runtime.h>
#include <math.h>

#define NC 64
#define NH 256
#define NW 256
#define NM 32
#define NKY 64
#define HW 65536

typedef short bfrag __attribute__((ext_vector_type(8)));   // 8 bf16 (4 VGPR)
typedef float facc  __attribute__((ext_vector_type(4)));   // 4 f32 acc
#define MFMA(a,b,c) __builtin_amdgcn_mfma_f32_16x16x32_bf16(a,b,c,0,0,0)

static constexpr float PI_F = 3.14159265358979323846f;

__device__ __forceinline__ unsigned short f2b(float f) {  // f32 -> bf16 RNE
  unsigned b = __float_as_uint(f);
  return (unsigned short)((b + 0x7FFFu + ((b >> 16) & 1u)) >> 16);
}
__device__ __forceinline__ float b2f(unsigned short h) {
  return __uint_as_float((unsigned)h << 16);
}

// branchless erf-based exact GELU (A&S 7.1.26, |err| < 1.5e-7)
__device__ __forceinline__ float gelu_f(float x) {
  float z = fabsf(x) * 0.70710678118654752f;
  float t = 1.0f / (1.0f + 0.3275911f * z);
  float e = __expf(-z * z);
  float p = t * (0.254829592f + t * (-0.284496736f + t * (1.421413741f +
            t * (-1.453152027f + t * 1.061405429f))));
  float er = copysignf(1.0f - p * e, x);
  return 0.5f * x * (1.0f + er);
}

// ================= table builders (split-bf16 DFT matrices) =================
// Ey [128][256]: rows 0..63 re, 64..127 im of forward y-DFT (e^{-i}); ky(m)=m<32?m:192+m
__global__ void k_tEy(unsigned short* __restrict__ eh, unsigned short* __restrict__ el) {
  int i = blockIdx.x * 256 + threadIdx.x;   // 32768
  int m = i >> 8, y = i & 255;
  int kyi = m & 63;
  int ky = (kyi < 32) ? kyi : (192 + kyi);
  int a = (ky * y) & 255;
  float s, c; sincosf((float)a * (PI_F / 128.f), &s, &c);
  float v = (m < 64) ? c : -s;
  unsigned short h = f2b(v);
  eh[i] = h; el[i] = f2b(v - b2f(h));
}
// Ex [64][512]: forward x-DFT on complex input, K-doubled (cols 0..255 re-in, 256..511 im-in)
__global__ void k_tEx(unsigned short* __restrict__ eh, unsigned short* __restrict__ el) {
  int i = blockIdx.x * 256 + threadIdx.x;   // 32768
  int m = i >> 9, k = i & 511;
  int x = k & 255, plane = k >> 8, kx = m & 31;
  int a = (kx * x) & 255;
  float s, c; sincosf((float)a * (PI_F / 128.f), &s, &c);
  float v = (m < 32) ? (plane ? s : c) : (plane ? c : -s);
  unsigned short h = f2b(v);
  eh[i] = h; el[i] = f2b(v - b2f(h));
}
// Wyi [512][128]: inverse y-DFT (e^{+i}); rows 0..255 t2r(y), 256..511 t2i(y); cols (Sr kyi | Si kyi)
__global__ void k_tWy(unsigned short* __restrict__ eh, unsigned short* __restrict__ el) {
  int i = blockIdx.x * 256 + threadIdx.x;   // 65536
  int row = i >> 7, k = i & 127;
  int y = row & 255, part = row >> 8;
  int kyi = k & 63, plane = k >> 6;
  int ky = (kyi < 32) ? kyi : (192 + kyi);
  int a = (ky * y) & 255;
  float s, c; sincosf((float)a * (PI_F / 128.f), &s, &c);
  float v = (part == 0) ? (plane ? -s : c) : (plane ? c : s);
  unsigned short h = f2b(v);
  eh[i] = h; el[i] = f2b(v - b2f(h));
}
// Cx [256][64]: inverse x c2r; rows = x; cols 0..31 t2r(kx), 32..63 t2i(kx); scale folded
__global__ void k_tCx(unsigned short* __restrict__ eh, unsigned short* __restrict__ el) {
  int i = blockIdx.x * 256 + threadIdx.x;   // 16384
  int x = i >> 6, k = i & 63;
  int kx = k & 31, plane = k >> 5;
  float w = ((kx == 0) ? 1.0f : 2.0f) / 65536.0f;
  int a = (kx * x) & 255;
  float s, c; sincosf((float)a * (PI_F / 128.f), &s, &c);
  float v = plane ? (-w * s) : (w * c);
  unsigned short h = f2b(v);
  eh[i] = h; el[i] = f2b(v - b2f(h));
}

// ---- init: f32 -> bf16 hi/lo split (weights)
__global__ void k_cvt2(const float* __restrict__ src, unsigned short* __restrict__ hi,
                       unsigned short* __restrict__ lo, int n) {
  int i = blockIdx.x * 256 + threadIdx.x;
  if (i < n) {
    float v = src[i];
    unsigned short h = f2b(v);
    hi[i] = h;
    lo[i] = f2b(v - b2f(h));
  }
}

// ---- lift
__global__ __launch_bounds__(256) void k_lift(const float* __restrict__ x,
                                              const float* __restrict__ pw,
                                              const float* __restrict__ pb,
                                              float* __restrict__ h) {
  int b = blockIdx.y;
  int yx = blockIdx.x * 256 + threadIdx.x;
  float v = x[(size_t)b * HW + yx];
  float* hp = h + (size_t)b * NC * HW + yx;
  for (int c = 0; c < NC; ++c) hp[(size_t)c * HW] = v * pw[c] + pb[c];
}

// ================= spectral GEMM stages (split-bf16 MFMA) =================
// forward y: Xc[128 rows][(bc,x)] = Ey . h   (M=128,K=256)
__global__ __launch_bounds__(256) void k_fy2(const float* __restrict__ h,
                                             const unsigned short* __restrict__ Ah,
                                             const unsigned short* __restrict__ Al,
                                             float* __restrict__ Xc, int Ncol) {
  int tid = threadIdx.x, wv = tid >> 6, ln = tid & 63, g16 = ln >> 4, l15 = ln & 15;
  int colbase = blockIdx.x * 128 + wv * 32;
  facc acc[8][2];
#pragma unroll
  for (int mf = 0; mf < 8; ++mf)
#pragma unroll
    for (int pf = 0; pf < 2; ++pf) acc[mf][pf] = (facc)0.f;
#pragma unroll 1
  for (int ks = 0; ks < 8; ++ks) {
    int kof = g16 * 8 + 32 * ks;
    bfrag bh[2], bl[2];
#pragma unroll
    for (int pf = 0; pf < 2; ++pf) {
      int col = colbase + pf * 16 + l15;
      const float* hp = h + (size_t)(col >> 8) * HW + (col & 255) + (size_t)kof * 256;
#pragma unroll
      for (int j = 0; j < 8; ++j) {
        float v = hp[j * 256];
        unsigned short hi = f2b(v);
        bh[pf][j] = (short)hi;
        bl[pf][j] = (short)f2b(v - b2f(hi));
      }
    }
#pragma unroll
    for (int mf = 0; mf < 8; ++mf) {
      int row = 16 * mf + l15;
      bfrag ah = *(const bfrag*)(Ah + row * 256 + kof);
      bfrag al = *(const bfrag*)(Al + row * 256 + kof);
#pragma unroll
      for (int pf = 0; pf < 2; ++pf) {
        acc[mf][pf] = MFMA(ah, bh[pf], acc[mf][pf]);
        acc[mf][pf] = MFMA(ah, bl[pf], acc[mf][pf]);
        acc[mf][pf] = MFMA(al, bh[pf], acc[mf][pf]);
      }
    }
  }
#pragma unroll
  for (int mf = 0; mf < 8; ++mf)
#pragma unroll
    for (int pf = 0; pf < 2; ++pf) {
      int col = colbase + pf * 16 + l15;
#pragma unroll
      for (int r = 0; r < 4; ++r)
        Xc[(size_t)(16 * mf + 4 * g16 + r) * Ncol + col] = acc[mf][pf][r];
    }
}

// forward x: X2[(bc,kyi)][kx] = Ex . Xc   (M=64,K=512; K-doubled complex)
__global__ __launch_bounds__(256) void k_fx2(const float* __restrict__ Xc,
                                             const unsigned short* __restrict__ Ah,
                                             const unsigned short* __restrict__ Al,
                                             float* __restrict__ X2r,
                                             float* __restrict__ X2i, int NcXc) {
  int tid = threadIdx.x, wv = tid >> 6, ln = tid & 63, g16 = ln >> 4, l15 = ln & 15;
  int colbase = blockIdx.x * 128 + wv * 32;
  facc acc[4][2];
#pragma unroll
  for (int mf = 0; mf < 4; ++mf)
#pragma unroll
    for (int pf = 0; pf < 2; ++pf) acc[mf][pf] = (facc)0.f;
#pragma unroll 1
  for (int ks = 0; ks < 16; ++ks) {
    int plane = ks >> 3;
    int x0 = (ks & 7) * 32 + g16 * 8;
    int kof = g16 * 8 + 32 * ks;
    bfrag bh[2], bl[2];
#pragma unroll
    for (int pf = 0; pf < 2; ++pf) {
      int col = colbase + pf * 16 + l15;
      const float* p = Xc + (size_t)(plane * 64 + (col & 63)) * NcXc + (col >> 6) * 256 + x0;
      float4 u0 = *(const float4*)p;
      float4 u1 = *(const float4*)(p + 4);
      float tv[8] = {u0.x, u0.y, u0.z, u0.w, u1.x, u1.y, u1.z, u1.w};
#pragma unroll
      for (int j = 0; j < 8; ++j) {
        unsigned short hi = f2b(tv[j]);
        bh[pf][j] = (short)hi;
        bl[pf][j] = (short)f2b(tv[j] - b2f(hi));
      }
    }
#pragma unroll
    for (int mf = 0; mf < 4; ++mf) {
      int row = 16 * mf + l15;
      bfrag ah = *(const bfrag*)(Ah + row * 512 + kof);
      bfrag al = *(const bfrag*)(Al + row * 512 + kof);
#pragma unroll
      for (int pf = 0; pf < 2; ++pf) {
        acc[mf][pf] = MFMA(ah, bh[pf], acc[mf][pf]);
        acc[mf][pf] = MFMA(ah, bl[pf], acc[mf][pf]);
        acc[mf][pf] = MFMA(al, bh[pf], acc[mf][pf]);
      }
    }
  }
#pragma unroll
  for (int mf = 0; mf < 4; ++mf)
#pragma unroll
    for (int pf = 0; pf < 2; ++pf) {
      int col = colbase + pf * 16 + l15;
      float* base = (mf >= 2) ? X2i : X2r;
      int kxb = 16 * (mf & 1) + 4 * g16;
      float4 v = make_float4(acc[mf][pf][0], acc[mf][pf][1], acc[mf][pf][2], acc[mf][pf][3]);
      *(float4*)(base + (size_t)col * 32 + kxb) = v;
    }
}

// ---- spectral channel mix (f32): S[(plane,kyi)][(bc,kx)] = X2 . W
__global__ __launch_bounds__(512) void k_spec(const float* __restrict__ X2r,
                                              const float* __restrict__ X2i,
                                              const float* __restrict__ w1r,
                                              const float* __restrict__ w1i,
                                              const float* __restrict__ w2r,
                                              const float* __restrict__ w2i,
                                              float* __restrict__ S, int Ncs) {
  int b = blockIdx.y;
  int och = blockIdx.x & 3;
  int kyi = blockIdx.x >> 2;
  __shared__ float2 xs[NC * NM];
  for (int idx = threadIdx.x; idx < NC * NM; idx += 512) {
    int i = idx >> 5, kx = idx & 31;
    size_t c2 = ((size_t)(b * 64 + i) * 64 + kyi) * 32 + kx;
    xs[idx] = make_float2(X2r[c2], X2i[c2]);
  }
  __syncthreads();
  int kx = threadIdx.x & 31;
  int ol = threadIdx.x >> 5;
  int o = och * 16 + ol;
  int kym = kyi & 31;
  const float* wr = (kyi < 32) ? w1r : w2r;
  const float* wi = (kyi < 32) ? w1i : w2i;
  size_t wb = ((size_t)o * NM + kym) * NM + kx;
  float ar = 0.f, ai = 0.f;
#pragma unroll 4
  for (int i = 0; i < NC; ++i) {
    float2 xv = xs[i * NM + kx];
    float wrv = wr[wb + (size_t)i * 65536];
    float wiv = wi[wb + (size_t)i * 65536];
    ar += xv.x * wrv - xv.y * wiv;
    ai += xv.x * wiv + xv.y * wrv;
  }
  size_t cco = (size_t)(b * 64 + o) * 32 + kx;
  S[(size_t)kyi * Ncs + cco] = ar;
  S[(size_t)(64 + kyi) * Ncs + cco] = ai;
}

// inverse y: t2[(plane,y)][(bc,kx)] = Wyi . S   (M=512,K=128)
__global__ __launch_bounds__(256) void k_iy2(const float* __restrict__ S,
                                             const unsigned short* __restrict__ Ah,
                                             const unsigned short* __restrict__ Al,
                                             float* __restrict__ t2, int Ncs) {
  int tid = threadIdx.x, wv = tid >> 6, ln = tid & 63, g16 = ln >> 4, l15 = ln & 15;
  int colbase = blockIdx.x * 128 + wv * 32;
  int rowb = blockIdx.y * 64;
  facc acc[4][2];
#pragma unroll
  for (int mf = 0; mf < 4; ++mf)
#pragma unroll
    for (int pf = 0; pf < 2; ++pf) acc[mf][pf] = (facc)0.f;
#pragma unroll 1
  for (int ks = 0; ks < 4; ++ks) {
    int kof = g16 * 8 + 32 * ks;
    bfrag bh[2], bl[2];
#pragma unroll
    for (int pf = 0; pf < 2; ++pf) {
      int col = colbase + pf * 16 + l15;
      const float* p = S + (size_t)kof * Ncs + col;
#pragma unroll
      for (int j = 0; j < 8; ++j) {
        float v = p[(size_t)j * Ncs];
        unsigned short hi = f2b(v);
        bh[pf][j] = (short)hi;
        bl[pf][j] = (short)f2b(v - b2f(hi));
      }
    }
#pragma unroll
    for (int mf = 0; mf < 4; ++mf) {
      int row = rowb + 16 * mf + l15;
      bfrag ah = *(const bfrag*)(Ah + row * 128 + kof);
      bfrag al = *(const bfrag*)(Al + row * 128 + kof);
#pragma unroll
      for (int pf = 0; pf < 2; ++pf) {
        acc[mf][pf] = MFMA(ah, bh[pf], acc[mf][pf]);
        acc[mf][pf] = MFMA(ah, bl[pf], acc[mf][pf]);
        acc[mf][pf] = MFMA(al, bh[pf], acc[mf][pf]);
      }
    }
  }
#pragma unroll
  for (int mf = 0; mf < 4; ++mf)
#pragma unroll
    for (int pf = 0; pf < 2; ++pf) {
      int col = colbase + pf * 16 + l15;
#pragma unroll
      for (int r = 0; r < 4; ++r)
        t2[(size_t)(rowb + 16 * mf + 4 * g16 + r) * Ncs + col] = acc[mf][pf][r];
    }
}

// inverse x (c2r): x1[bc][y][x] = Cx . t2   (M=256,K=64); bf16 hi/lo output
__global__ __launch_bounds__(256) void k_ix2(const float* __restrict__ t2,
                                             const unsigned short* __restrict__ Ah,
                                             const unsigned short* __restrict__ Al,
                                             unsigned short* __restrict__ x1h,
                                             unsigned short* __restrict__ x1l, int Nct) {
  int tid = threadIdx.x, wv = tid >> 6, ln = tid & 63, g16 = ln >> 4, l15 = ln & 15;
  int colbase = blockIdx.x * 128 + wv * 32;
  int rowb = blockIdx.y * 128;
  facc acc[8][2];
#pragma unroll
  for (int mf = 0; mf < 8; ++mf)
#pragma unroll
    for (int pf = 0; pf < 2; ++pf) acc[mf][pf] = (facc)0.f;
#pragma unroll 1
  for (int ks = 0; ks < 2; ++ks) {
    int kof = g16 * 8 + 32 * ks;
    bfrag bh[2], bl[2];
#pragma unroll
    for (int pf = 0; pf < 2; ++pf) {
      int col = colbase + pf * 16 + l15;
      const float* p = t2 + (size_t)(ks * 256 + (col & 255)) * Nct + (col >> 8) * 32 + g16 * 8;
      float4 u0 = *(const float4*)p;
      float4 u1 = *(const float4*)(p + 4);
      float tv[8] = {u0.x, u0.y, u0.z, u0.w, u1.x, u1.y, u1.z, u1.w};
#pragma unroll
      for (int j = 0; j < 8; ++j) {
        unsigned short hi = f2b(tv[j]);
        bh[pf][j] = (short)hi;
        bl[pf][j] = (short)f2b(tv[j] - b2f(hi));
      }
    }
#pragma unroll
    for (int mf = 0; mf < 8; ++mf) {
      int row = rowb + 16 * mf + l15;
      bfrag ah = *(const bfrag*)(Ah + row * 64 + kof);
      bfrag al = *(const bfrag*)(Al + row * 64 + kof);
#pragma unroll
      for (int pf = 0; pf < 2; ++pf) {
        acc[mf][pf] = MFMA(ah, bh[pf], acc[mf][pf]);
        acc[mf][pf] = MFMA(ah, bl[pf], acc[mf][pf]);
        acc[mf][pf] = MFMA(al, bh[pf], acc[mf][pf]);
      }
    }
  }
#pragma unroll
  for (int mf = 0; mf < 8; ++mf)
#pragma unroll
    for (int pf = 0; pf < 2; ++pf) {
      int col = colbase + pf * 16 + l15;
      int bc = col >> 8, y = col & 255;
      int xb = rowb + 16 * mf + 4 * g16;
      ushort4 hv, lv;
#pragma unroll
      for (int r = 0; r < 4; ++r) {
        float v = acc[mf][pf][r];
        unsigned short hi = f2b(v);
        ((unsigned short*)&hv)[r] = hi;
        ((unsigned short*)&lv)[r] = f2b(v - b2f(hi));
      }
      size_t o = (size_t)bc * HW + y * 256 + xb;
      *(ushort4*)(x1h + o) = hv;
      *(ushort4*)(x1l + o) = lv;
    }
}

// ---- MLP conv1 + GELU via split-bf16 MFMA; in-place x1 pair -> mid pair
__global__ __launch_bounds__(256) void k_mlp1s(unsigned short* __restrict__ x1h,
                                               unsigned short* __restrict__ x1l,
                                               const unsigned short* __restrict__ w1h,
                                               const unsigned short* __restrict__ w1l,
                                               const float* __restrict__ b1p) {
  __shared__ unsigned short whs[64 * 72], wls[64 * 72];
  int tid = threadIdx.x;
  for (int i = tid; i < 64 * 64; i += 256) {
    int r = i >> 6, c = i & 63;
    whs[r * 72 + c] = w1h[i];
    wls[r * 72 + c] = w1l[i];
  }
  int wv = tid >> 6, ln = tid & 63, g16 = ln >> 4, l15 = ln & 15;
  int b = blockIdx.y;
  unsigned short* xh = x1h + (size_t)b * NC * HW;
  unsigned short* xl = x1l + (size_t)b * NC * HW;
  float b1v[4][4];
#pragma unroll
  for (int mf = 0; mf < 4; ++mf)
#pragma unroll
    for (int r = 0; r < 4; ++r) b1v[mf][r] = b1p[16 * mf + 4 * g16 + r];
  __syncthreads();
  for (int t = 0; t < 4; ++t) {
    int pxb = (blockIdx.x * 4 + t) * 128 + wv * 32;
    facc a1[4][2];
#pragma unroll
    for (int mf = 0; mf < 4; ++mf)
#pragma unroll
      for (int pf = 0; pf < 2; ++pf) {
        facc z; z[0] = b1v[mf][0]; z[1] = b1v[mf][1]; z[2] = b1v[mf][2]; z[3] = b1v[mf][3];
        a1[mf][pf] = z;
      }
#pragma unroll
    for (int ks = 0; ks < 2; ++ks) {
      bfrag xhb[2], xlb[2];
#pragma unroll
      for (int pf = 0; pf < 2; ++pf) {
        int px = pxb + pf * 16 + l15;
#pragma unroll
        for (int j = 0; j < 8; ++j) {
          int c = g16 * 8 + j + 32 * ks;
          xhb[pf][j] = (short)xh[(size_t)c * HW + px];
          xlb[pf][j] = (short)xl[(size_t)c * HW + px];
        }
      }
#pragma unroll
      for (int mf = 0; mf < 4; ++mf) {
        bfrag wh = *(const bfrag*)(whs + (16 * mf + l15) * 72 + g16 * 8 + 32 * ks);
        bfrag wl = *(const bfrag*)(wls + (16 * mf + l15) * 72 + g16 * 8 + 32 * ks);
#pragma unroll
        for (int pf = 0; pf < 2; ++pf) {
          a1[mf][pf] = MFMA(wh, xhb[pf], a1[mf][pf]);
          a1[mf][pf] = MFMA(wh, xlb[pf], a1[mf][pf]);
          a1[mf][pf] = MFMA(wl, xhb[pf], a1[mf][pf]);
        }
      }
    }
#pragma unroll
    for (int mf = 0; mf < 4; ++mf)
#pragma unroll
      for (int pf = 0; pf < 2; ++pf) {
        int px = pxb + pf * 16 + l15;
#pragma unroll
        for (int r = 0; r < 4; ++r) {
          float v = gelu_f(a1[mf][pf][r]);
          unsigned short hi = f2b(v);
          size_t idx = (size_t)(16 * mf + 4 * g16 + r) * HW + px;
          xh[idx] = hi;
          xl[idx] = f2b(v - b2f(hi));
        }
      }
  }
}

// ---- conv2 + skip + add (+GELU) via split-bf16 MFMA; h (f32) updated in place
__global__ __launch_bounds__(256) void k_mix2(const unsigned short* __restrict__ midh,
                                              const unsigned short* __restrict__ midl,
                                              float* __restrict__ h,
                                              const unsigned short* __restrict__ w2h,
                                              const unsigned short* __restrict__ w2l,
                                              const unsigned short* __restrict__ skh,
                                              const unsigned short* __restrict__ skl,
                                              const float* __restrict__ b2p,
                                              const float* __restrict__ skbp,
                                              int do_gelu) {
  __shared__ unsigned short w2hs[64 * 72], w2ls[64 * 72], skhs[64 * 72], skls[64 * 72];
  int tid = threadIdx.x;
  for (int i = tid; i < 64 * 64; i += 256) {
    int r = i >> 6, c = i & 63;
    w2hs[r * 72 + c] = w2h[i];
    w2ls[r * 72 + c] = w2l[i];
    skhs[r * 72 + c] = skh[i];
    skls[r * 72 + c] = skl[i];
  }
  int wv = tid >> 6, ln = tid & 63, g16 = ln >> 4, l15 = ln & 15;
  int b = blockIdx.y;
  const unsigned short* mh = midh + (size_t)b * NC * HW;
  const unsigned short* ml = midl + (size_t)b * NC * HW;
  float* hb = h + (size_t)b * NC * HW;
  float b2v[4][4];
#pragma unroll
  for (int mf = 0; mf < 4; ++mf)
#pragma unroll
    for (int r = 0; r < 4; ++r) {
      int o = 16 * mf + 4 * g16 + r;
      b2v[mf][r] = b2p[o] + skbp[o];
    }
  __syncthreads();
  for (int t = 0; t < 4; ++t) {
    int pxb = (blockIdx.x * 4 + t) * 128 + wv * 32;
    facc a2[4][2];
#pragma unroll
    for (int mf = 0; mf < 4; ++mf)
#pragma unroll
      for (int pf = 0; pf < 2; ++pf) {
        facc z; z[0] = b2v[mf][0]; z[1] = b2v[mf][1]; z[2] = b2v[mf][2]; z[3] = b2v[mf][3];
        a2[mf][pf] = z;
      }
#pragma unroll
    for (int ks = 0; ks < 2; ++ks) {
      bfrag mhb[2], mlb[2], hhb[2], hlb[2];
#pragma unroll
      for (int pf = 0; pf < 2; ++pf) {
        int px = pxb + pf * 16 + l15;
#pragma unroll
        for (int j = 0; j < 8; ++j) {
          int c = g16 * 8 + j + 32 * ks;
          mhb[pf][j] = (short)mh[(size_t)c * HW + px];
          mlb[pf][j] = (short)ml[(size_t)c * HW + px];
          float v = hb[(size_t)c * HW + px];
          unsigned short hi = f2b(v);
          hhb[pf][j] = (short)hi;
          hlb[pf][j] = (short)f2b(v - b2f(hi));
        }
      }
#pragma unroll
      for (int mf = 0; mf < 4; ++mf) {
        bfrag w2hf = *(const bfrag*)(w2hs + (16 * mf + l15) * 72 + g16 * 8 + 32 * ks);
        bfrag w2lf = *(const bfrag*)(w2ls + (16 * mf + l15) * 72 + g16 * 8 + 32 * ks);
        bfrag skhf = *(const bfrag*)(skhs + (16 * mf + l15) * 72 + g16 * 8 + 32 * ks);
        bfrag sklf = *(const bfrag*)(skls + (16 * mf + l15) * 72 + g16 * 8 + 32 * ks);
#pragma unroll
        for (int pf = 0; pf < 2; ++pf) {
          a2[mf][pf] = MFMA(w2hf, mhb[pf], a2[mf][pf]);
          a2[mf][pf] = MFMA(w2hf, mlb[pf], a2[mf][pf]);
          a2[mf][pf] = MFMA(w2lf, mhb[pf], a2[mf][pf]);
          a2[mf][pf] = MFMA(skhf, hhb[pf], a2[mf][pf]);
          a2[mf][pf] = MFMA(skhf, hlb[pf], a2[mf][pf]);
          a2[mf][pf] = MFMA(sklf, hhb[pf], a2[mf][pf]);
        }
      }
    }
#pragma unroll
    for (int mf = 0; mf < 4; ++mf)
#pragma unroll
      for (int pf = 0; pf < 2; ++pf) {
        facc v = a2[mf][pf];
        if (do_gelu) {
          v[0] = gelu_f(v[0]); v[1] = gelu_f(v[1]);
          v[2] = gelu_f(v[2]); v[3] = gelu_f(v[3]);
        }
        int px = pxb + pf * 16 + l15;
#pragma unroll
        for (int r = 0; r < 4; ++r)
          hb[(size_t)(16 * mf + 4 * g16 + r) * HW + px] = v[r];
      }
  }
}

// ---- projection via split-bf16 MFMA; q1 fragments in registers
__global__ __launch_bounds__(256) void k_proj2s(const float* __restrict__ h,
                                                const unsigned short* __restrict__ q1h,
                                                const unsigned short* __restrict__ q1l,
                                                const float* __restrict__ q1bp,
                                                const float* __restrict__ q2wp,
                                                const float* __restrict__ q2bp,
                                                float* __restrict__ out) {
  __shared__ float part[4][16];
  int tid = threadIdx.x;
  int wv = tid >> 6, ln = tid & 63, g16 = ln >> 4, l15 = ln & 15;
  int b = blockIdx.y;
  const float* hb = h + (size_t)b * NC * HW;
  bfrag qh[4][2], ql[4][2];
#pragma unroll
  for (int mf = 0; mf < 4; ++mf)
#pragma unroll
    for (int ks = 0; ks < 2; ++ks) {
      int row = 64 * wv + 16 * mf + l15;
      size_t base = (size_t)row * 64 + g16 * 8 + 32 * ks;
      qh[mf][ks] = *(const bfrag*)(q1h + base);
      ql[mf][ks] = *(const bfrag*)(q1l + base);
    }
  float bq[4][4], qv[4][4];
#pragma unroll
  for (int mf = 0; mf < 4; ++mf)
#pragma unroll
    for (int r = 0; r < 4; ++r) {
      int row = 64 * wv + 16 * mf + 4 * g16 + r;
      bq[mf][r] = q1bp[row];
      qv[mf][r] = q2wp[row];
    }
  float q2bias = q2bp[0];
  for (int t = 0; t < 16; ++t) {
    int px0 = blockIdx.x * 256 + t * 16;
    facc acc[4];
#pragma unroll
    for (int mf = 0; mf < 4; ++mf) {
      facc z; z[0] = bq[mf][0]; z[1] = bq[mf][1]; z[2] = bq[mf][2]; z[3] = bq[mf][3];
      acc[mf] = z;
    }
#pragma unroll
    for (int ks = 0; ks < 2; ++ks) {
      bfrag hh, hl;
#pragma unroll
      for (int j = 0; j < 8; ++j) {
        int c = g16 * 8 + j + 32 * ks;
        float v = hb[(size_t)c * HW + px0 + l15];
        unsigned short hi = f2b(v);
        hh[j] = (short)hi;
        hl[j] = (short)f2b(v - b2f(hi));
      }
#pragma unroll
      for (int mf = 0; mf < 4; ++mf) {
        acc[mf] = MFMA(qh[mf][ks], hh, acc[mf]);
        acc[mf] = MFMA(qh[mf][ks], hl, acc[mf]);
        acc[mf] = MFMA(ql[mf][ks], hh, acc[mf]);
      }
    }
    float partial = 0.f;
#pragma unroll
    for (int mf = 0; mf < 4; ++mf)
#pragma unroll
      for (int r = 0; r < 4; ++r)
        partial += gelu_f(acc[mf][r]) * qv[mf][r];
    partial += __shfl_xor(partial, 16);
    partial += __shfl_xor(partial, 32);
    if (ln < 16) part[wv][l15] = partial;
    __syncthreads();
    if (tid < 16)
      out[(size_t)b * HW + px0 + tid] =
          part[0][tid] + part[1][tid] + part[2][tid] + part[3][tid] + q2bias;
    __syncthreads();
  }
}

extern "C" void kernel_launch(void* const* d_in, const int* in_sizes, int n_in,
                              void* d_out, int out_size, void* d_ws, size_t ws_size,
                              hipStream_t stream) {
  const float* x    = (const float*)d_in[0];
  const float* p_w  = (const float*)d_in[1];
  const float* p_b  = (const float*)d_in[2];
  const float* sw1r = (const float*)d_in[3];
  const float* sw1i = (const float*)d_in[4];
  const float* sw2r = (const float*)d_in[5];
  const float* sw2i = (const float*)d_in[6];
  const float* m1w  = (const float*)d_in[7];
  const float* m1b  = (const float*)d_in[8];
  const float* m2w  = (const float*)d_in[9];
  const float* m2b  = (const float*)d_in[10];
  const float* skw  = (const float*)d_in[11];
  const float* skb  = (const float*)d_in[12];
  const float* q1w  = (const float*)d_in[13];
  const float* q1b  = (const float*)d_in[14];
  const float* q2w  = (const float*)d_in[15];
  const float* q2b  = (const float*)d_in[16];

  // Per-batch live set: A (h f32, 16MB) + x1 pair (16MB; spectral temps Xc/X2/S
  // alias its dead regions) + t2 (4MB, live across k_ix2) = 36 MB. Tables: 1MB.
  const size_t MB = 1048576ULL;
  const size_t TBL = 1 * MB;
  int g = 16;
  while (g > 1 && (size_t)g * 36 * MB + TBL > ws_size) g >>= 1;
  if ((size_t)g * 36 * MB + TBL > ws_size) return;

  char* wsb = (char*)d_ws;
  unsigned short* Eyh = (unsigned short*)(wsb + 0);        // 64 KB
  unsigned short* Eyl = (unsigned short*)(wsb + 65536);
  unsigned short* Exh = (unsigned short*)(wsb + 131072);   // 64 KB
  unsigned short* Exl = (unsigned short*)(wsb + 196608);
  unsigned short* Wyh = (unsigned short*)(wsb + 262144);   // 128 KB
  unsigned short* Wyl = (unsigned short*)(wsb + 393216);
  unsigned short* Cxh = (unsigned short*)(wsb + 524288);   // 32 KB
  unsigned short* Cxl = (unsigned short*)(wsb + 557056);
  unsigned short* m1h = (unsigned short*)(wsb + 589824);   // 32 KB each
  unsigned short* m1l = (unsigned short*)(wsb + 622592);
  unsigned short* m2h = (unsigned short*)(wsb + 655360);
  unsigned short* m2l = (unsigned short*)(wsb + 688128);
  unsigned short* skh = (unsigned short*)(wsb + 720896);
  unsigned short* skl = (unsigned short*)(wsb + 753664);
  unsigned short* q1h = (unsigned short*)(wsb + 786432);
  unsigned short* q1l = (unsigned short*)(wsb + 819200);

  char* base = wsb + TBL;
  float* A = (float*)base;                                          // g*16 MB
  unsigned short* x1h = (unsigned short*)(base + (size_t)g * 16 * MB);  // g*8 MB
  unsigned short* x1l = (unsigned short*)(base + (size_t)g * 24 * MB);  // g*8 MB
  float* Xc  = (float*)x1h;                                         // alias g*8 MB
  float* X2r = (float*)x1l;                                         // alias g*0.5 MB
  float* X2i = (float*)((char*)x1l + (size_t)g * 512 * 1024);       // alias g*0.5 MB
  float* S   = (float*)((char*)x1l + (size_t)g * 1 * MB);           // alias g*1 MB
  float* t2  = (float*)(base + (size_t)g * 32 * MB);                // g*4 MB

  k_tEy<<<128, 256, 0, stream>>>(Eyh, Eyl);
  k_tEx<<<128, 256, 0, stream>>>(Exh, Exl);
  k_tWy<<<256, 256, 0, stream>>>(Wyh, Wyl);
  k_tCx<<<64, 256, 0, stream>>>(Cxh, Cxl);
  k_cvt2<<<64, 256, 0, stream>>>(m1w, m1h, m1l, 16384);
  k_cvt2<<<64, 256, 0, stream>>>(m2w, m2h, m2l, 16384);
  k_cvt2<<<64, 256, 0, stream>>>(skw, skh, skl, 16384);
  k_cvt2<<<64, 256, 0, stream>>>(q1w, q1h, q1l, 16384);

  int Nfy = g * 16384;   // (bc,x) cols
  int Ncs = g * 2048;    // (bc,kx) cols

  for (int b0 = 0; b0 < 16; b0 += g) {
    k_lift<<<dim3(256, g), 256, 0, stream>>>(x + (size_t)b0 * HW, p_w, p_b, A);
    for (int l = 0; l < 4; ++l) {
      k_fy2<<<g * 128, 256, 0, stream>>>(A, Eyh, Eyl, Xc, Nfy);
      k_fx2<<<g * 32, 256, 0, stream>>>(Xc, Exh, Exl, X2r, X2i, Nfy);
      k_spec<<<dim3(256, g), 512, 0, stream>>>(X2r, X2i,
                                               sw1r + (size_t)l * 4194304,
                                               sw1i + (size_t)l * 4194304,
                                               sw2r + (size_t)l * 4194304,
                                               sw2i + (size_t)l * 4194304, S, Ncs);
      k_iy2<<<dim3(g * 16, 8), 256, 0, stream>>>(S, Wyh, Wyl, t2, Ncs);
      k_ix2<<<dim3(g * 128, 2), 256, 0, stream>>>(t2, Cxh, Cxl, x1h, x1l, Ncs);
      k_mlp1s<<<dim3(128, g), 256, 0, stream>>>(x1h, x1l, m1h + l * 4096, m1l + l * 4096,
                                                m1b + l * 64);
      k_mix2<<<dim3(128, g), 256, 0, stream>>>(x1h, x1l, A, m2h + l * 4096, m2l + l * 4096,
                                               skh + l * 4096, skl + l * 4096,
                                               m2b + l * 64, skb + l * 64, (l < 3) ? 1 : 0);
    }
    k_proj2s<<<dim3(256, g), 256, 0, stream>>>(A, q1h, q1l, q1b, q2w, q2b,
                                               (float*)d_out + (size_t)b0 * HW);
  }
}